// Round 7
// baseline (320.920 us; speedup 1.0000x reference)
//
#include <hip/hip_runtime.h>

#define N_PTS 131072
#define K_CODES 1024
#define DIM 64
#define DECAYF 0.99f
#define OMDF 0.01f
#define EPSF 1e-5f

#define TAIL_BLKS 256   // 1 block/CU on 256 CUs -> co-residency guaranteed at ANY VGPR count

// ---- d_out layout (float elements, reference return order) ----
#define OUT_ZQ      0                  // [N, D]
#define OUT_LOSS    8388608            // scalar
#define OUT_IDX     8388609            // [N] (indices as floats)
#define OUT_NEWEMB  8519681            // [K, D]
#define OUT_NEWCS   8585217            // [K]
#define OUT_NEWEMA  8586241            // [K, D]

// ---- ws layout (float elements) ----
// zero region: [0, WS_ZERO_END) — zeroed by econv's grid-stride loop
#define WS_C8       0                  // 8*K floats
#define WS_ACNT     8192               // 16 ints: [0]=ambig_cnt, [8]=bar_cnt, [9]=bar_gen
#define WS_LOSS     8208               // 16 floats
#define WS_EMBSUM   8224               // K*D floats (atomic accumulator)
#define WS_ZERO_END 73760
#define WS_ENORM    73760              // K
#define WS_CUR8     74784              // 8*K ints
#define WS_CS       82976              // K
#define WS_AMBIG    84000              // N ints
#define WS_ORDER    215072             // N ints (packed code<<17|row)
// E2S aliases ORDER: E2S consumed by the argmin dispatch; ORDER written by
// the later vq_tail dispatch — disjoint in time across a dispatch boundary.
#define WS_E2S      215072

// E2S step layout (bytes, per step s of 64 codes = 4 tiles):
//   [0,16384): B frags, short addr = tau*2048 + p*512 + q*128 + c*8
//   [16384,16640): enorm[tau*16+c] as float
#define STEP_BYTES  16640
#define STEP_SHORTS 8320
#define STEP_FLOATS 4160

typedef __attribute__((ext_vector_type(8))) short bf16x8;
typedef __attribute__((ext_vector_type(4))) float f32x4;

static __device__ inline short f2bf(float f) {
    unsigned u = __float_as_uint(f);
    unsigned r = (u + 0x7fffu + ((u >> 16) & 1u)) >> 16;   // RNE
    return (short)r;
}
static __device__ inline float bf2f(short h) {
    return __uint_as_float(((unsigned)(unsigned short)h) << 16);
}

static __device__ __forceinline__ void gload16(const char* g, char* l) {
    __builtin_amdgcn_global_load_lds(
        (const __attribute__((address_space(1))) void*)g,
        (__attribute__((address_space(3))) void*)l, 16, 0, 0);
}
static __device__ __forceinline__ void gload4(const char* g, char* l) {
    __builtin_amdgcn_global_load_lds(
        (const __attribute__((address_space(1))) void*)g,
        (__attribute__((address_space(3))) void*)l, 4, 0, 0);
}

// Zero the ws accumulator region + E -> E2S (staged layout of bf16 hi/lo
// split of -2E, plus per-step enorm tail) + global enorm fp32 (for rescue).
// 4 threads per code. Absorbs the former hipMemsetAsync dispatch.
__global__ __launch_bounds__(256) void econv_kernel(const float* __restrict__ E,
                                                    float* __restrict__ ws) {
    int tid = threadIdx.x;
    int gid = blockIdx.x * 256 + tid;
    // zero accumulators (counts8, ambig_cnt, barrier, loss, embsum)
    for (int i = gid; i < WS_ZERO_END; i += 16 * 256) ws[i] = 0.f;

    short* E2S = (short*)(ws + WS_E2S);
    float* enorm = ws + WS_ENORM;
    int code = blockIdx.x * 64 + (tid >> 2);
    int seg = tid & 3;
    const float4* e4 = (const float4*)(E + (size_t)code * DIM + seg * 16);
    float4 v0 = e4[0], v1 = e4[1], v2 = e4[2], v3 = e4[3];
    float f[16];
    f[0]=v0.x; f[1]=v0.y; f[2]=v0.z; f[3]=v0.w;
    f[4]=v1.x; f[5]=v1.y; f[6]=v1.z; f[7]=v1.w;
    f[8]=v2.x; f[9]=v2.y; f[10]=v2.z; f[11]=v2.w;
    f[12]=v3.x; f[13]=v3.y; f[14]=v3.z; f[15]=v3.w;
    float s = 0.f;
#pragma unroll
    for (int j = 0; j < 16; ++j) s += f[j] * f[j];
    s += __shfl_xor(s, 1);
    s += __shfl_xor(s, 2);
    short hi[16], lo[16];
#pragma unroll
    for (int j = 0; j < 16; ++j) {
        float m = -2.f * f[j];
        short h = f2bf(m);
        hi[j] = h;
        lo[j] = f2bf(m - bf2f(h));
    }
    int sstep = code >> 6;
    int tau = (code >> 4) & 3;
    int cc = code & 15;
    size_t stepb = (size_t)sstep * STEP_SHORTS;
    int p_hi = seg >> 1, p_lo = 2 + (seg >> 1);
#pragma unroll
    for (int h8 = 0; h8 < 2; ++h8) {
        int qq = ((seg & 1) << 1) | h8;
        size_t base = stepb + tau * 2048 + qq * 128 + cc * 8;
        bf16x8 vh, vl;
#pragma unroll
        for (int j = 0; j < 8; ++j) { vh[j] = hi[h8 * 8 + j]; vl[j] = lo[h8 * 8 + j]; }
        *(bf16x8*)(E2S + base + p_hi * 512) = vh;
        *(bf16x8*)(E2S + base + p_lo * 512) = vl;
    }
    if (seg == 0) {
        ((float*)E2S)[(size_t)sstep * STEP_FLOATS + 4096 + tau * 16 + cc] = s;
        enorm[code] = s;
    }
}

// 512 blocks x 256 thr; wave = 64 rows (4 m-tiles) x all 1024 codes.
// B operand double-buffer-staged in LDS per BLOCK (proven R4 form, 71us).
__global__ __launch_bounds__(256) void argmin_mfma(const float* __restrict__ z,
                                                   const short* __restrict__ E2S,
                                                   float* __restrict__ out_idx_f,
                                                   float* __restrict__ counts8,
                                                   int* __restrict__ ambig_cnt,
                                                   int* __restrict__ ambig,
                                                   float* __restrict__ loss_ws) {
    int tid = threadIdx.x;
    int w = tid >> 6, lane = tid & 63;
    int c = lane & 15, q = lane >> 4;
    int mbase = blockIdx.x * 256 + w * 64;

    __shared__ char smem[2 * STEP_BYTES] __attribute__((aligned(16)));
    const char* E2Sc = (const char*)E2S;

#define STAGE(SBUF, SSTEP) do {                                               \
    const char* g_ = E2Sc + (size_t)(SSTEP) * STEP_BYTES + w * 1024 + lane * 16; \
    char* l_ = smem + (SBUF) * STEP_BYTES + w * 1024;                         \
    gload16(g_,          l_);                                                 \
    gload16(g_ + 4096,   l_ + 4096);                                          \
    gload16(g_ + 8192,   l_ + 8192);                                          \
    gload16(g_ + 12288,  l_ + 12288);                                         \
    if (w == 0)                                                               \
        gload4(E2Sc + (size_t)(SSTEP) * STEP_BYTES + 16384 + lane * 4,        \
               smem + (SBUF) * STEP_BYTES + 16384);                           \
} while (0)

    // issue step-0 staging first; A-prep global loads hide its latency
    STAGE(0, 0);

    bf16x8 a[4][4];   // [t][p]: p= 0:hi d0-31, 1:hi d32-63, 2:lo d0-31, 3:lo d32-63
    float znorm_t[4];
#pragma unroll
    for (int t = 0; t < 4; ++t) {
        const float* zp = z + (size_t)(mbase + t * 16 + c) * DIM;
        const float4* z4a = (const float4*)(zp + q * 8);
        const float4* z4b = (const float4*)(zp + 32 + q * 8);
        float f[16];
        float4 v0 = z4a[0], v1 = z4a[1], v2 = z4b[0], v3 = z4b[1];
        f[0]=v0.x; f[1]=v0.y; f[2]=v0.z; f[3]=v0.w;
        f[4]=v1.x; f[5]=v1.y; f[6]=v1.z; f[7]=v1.w;
        f[8]=v2.x; f[9]=v2.y; f[10]=v2.z; f[11]=v2.w;
        f[12]=v3.x; f[13]=v3.y; f[14]=v3.z; f[15]=v3.w;
        float zn = 0.f;
#pragma unroll
        for (int j = 0; j < 16; ++j) zn += f[j] * f[j];
#pragma unroll
        for (int off = 16; off < 64; off <<= 1) zn += __shfl_xor(zn, off);
        znorm_t[t] = zn;
#pragma unroll
        for (int j = 0; j < 8; ++j) {
            short h0 = f2bf(f[j]);
            a[t][0][j] = h0;
            a[t][2][j] = f2bf(f[j] - bf2f(h0));
            short h1 = f2bf(f[8 + j]);
            a[t][1][j] = h1;
            a[t][3][j] = f2bf(f[8 + j] - bf2f(h1));
        }
    }

    float s1[16], s2[16];
#pragma unroll
    for (int idx = 0; idx < 16; ++idx) { s1[idx] = INFINITY; s2[idx] = INFINITY; }

    __syncthreads();   // step-0 staging drained (vmcnt 0 before barrier)

    int bfr = (q << 4) + c;   // B frag unit index within a p-block
    for (int st = 0; st < 16; ++st) {
        if (st < 15) STAGE((st + 1) & 1, st + 1);
        const short* lb = (const short*)(smem + (st & 1) * STEP_BYTES);
        const float* lef = (const float*)(smem + (st & 1) * STEP_BYTES + 16384);
#pragma unroll
        for (int tau = 0; tau < 4; ++tau) {
            const bf16x8* bp = (const bf16x8*)lb + tau * 256 + bfr;
            bf16x8 bh0 = bp[0], bh1 = bp[64], bl0 = bp[128], bl1 = bp[192];
            float en = lef[tau * 16 + c];
            unsigned vcode = (unsigned)((((st << 2) + tau) << 4) | c);
#pragma unroll
            for (int t = 0; t < 4; ++t) {
                f32x4 acc = {en, en, en, en};
                acc = __builtin_amdgcn_mfma_f32_16x16x32_bf16(a[t][0], bl0, acc, 0, 0, 0);
                acc = __builtin_amdgcn_mfma_f32_16x16x32_bf16(a[t][1], bl1, acc, 0, 0, 0);
                acc = __builtin_amdgcn_mfma_f32_16x16x32_bf16(a[t][2], bh0, acc, 0, 0, 0);
                acc = __builtin_amdgcn_mfma_f32_16x16x32_bf16(a[t][3], bh1, acc, 0, 0, 0);
                acc = __builtin_amdgcn_mfma_f32_16x16x32_bf16(a[t][0], bh0, acc, 0, 0, 0);
                acc = __builtin_amdgcn_mfma_f32_16x16x32_bf16(a[t][1], bh1, acc, 0, 0, 0);
#pragma unroll
                for (int i = 0; i < 4; ++i) {
                    float sp = __uint_as_float(
                        (__float_as_uint(acc[i]) & 0xFFFFFC00u) | vcode);
                    int idx = t * 4 + i;
                    float ns2 = __builtin_amdgcn_fmed3f(s1[idx], s2[idx], sp);
                    s1[idx] = fminf(s1[idx], sp);
                    s2[idx] = ns2;
                }
            }
        }
        __syncthreads();
    }
#undef STAGE

#pragma unroll
    for (int off = 1; off < 16; off <<= 1) {
#pragma unroll
        for (int idx = 0; idx < 16; ++idx) {
            float os1 = __shfl_xor(s1[idx], off);
            float os2 = __shfl_xor(s2[idx], off);
            float ns1 = fminf(s1[idx], os1);
            s2[idx] = fminf(fmaxf(s1[idx], os1), fminf(s2[idx], os2));
            s1[idx] = ns1;
        }
    }

    float znr[16];
#pragma unroll
    for (int t = 0; t < 4; ++t)
#pragma unroll
        for (int i = 0; i < 4; ++i)
            znr[t * 4 + i] = __shfl(znorm_t[t], (q << 4) | (q * 4 + i), 64);

    float* lred = (float*)smem;   // staging buffers dead after loop
    float lsum = 0.f;
    if (c == 0) {
#pragma unroll
        for (int idx = 0; idx < 16; ++idx) {
            int t = idx >> 2, i = idx & 3;
            int row = mbase + t * 16 + q * 4 + i;
            unsigned b1 = __float_as_uint(s1[idx]);
            int code = (int)(b1 & 1023u);
            out_idx_f[row] = (float)code;
            float s1v = __uint_as_float(b1 & 0xFFFFFC00u);
            float gap = s2[idx] - s1[idx];
            float tau = 0.008f + 8e-4f * (fabsf(s1[idx]) + fabsf(s2[idx]));
            if (gap >= tau) {
                atomicAdd(&counts8[(((unsigned)row >> 8) & 7) * K_CODES + code], 1.0f);
                lsum += znr[idx] + s1v;
            } else {
                int p = atomicAdd(ambig_cnt, 1);
                ambig[p] = row;
            }
        }
        lred[w * 4 + q] = lsum;
    }
    __syncthreads();
    if (tid == 0) {
        float tot = 0.f;
#pragma unroll
        for (int i = 0; i < 16; ++i) tot += lred[i];
        atomicAdd(loss_ws, tot);
    }
}

// Software global barrier. 256 blocks at 1 block/CU — co-residency is
// unconditional. atomicExch reset (plain-store reset can be stale to
// remote atomics); release fence before arrive, acquire after gen flip.
static __device__ __forceinline__ void gbar(int* bar_cnt, int* bar_gen, int nblk) {
    __syncthreads();
    if (threadIdx.x == 0) {
        __threadfence();                       // release prior plain stores
        int g = atomicAdd(bar_gen, 0);
        if (atomicAdd(bar_cnt, 1) == nblk - 1) {
            atomicExch(bar_cnt, 0);
            __threadfence();
            atomicAdd(bar_gen, 1);
        } else {
            while (atomicAdd(bar_gen, 0) == g) __builtin_amdgcn_s_sleep(8);
        }
        __threadfence();                       // acquire
    }
    __syncthreads();
}

// Fused tail: rescue -> scan -> scatter+zq -> segsum -> ema2. Replaces 5
// dispatches with 4 in-kernel barriers. Rescue is the R4 kernel body
// VERBATIM (2 rows/wave): razor-tie rows (top-2 gap < fp32 noise) are
// coin-flips vs the numpy reference, decided by compiled FP rounding —
// keeping the exact R4 expression DAG keeps the R4 (passing) rounding.
__global__ __launch_bounds__(256) void vq_tail(const float* __restrict__ z,
                                               const float* __restrict__ E,
                                               const float* __restrict__ cluster_size,
                                               const float* __restrict__ ema,
                                               float* __restrict__ out,
                                               float* __restrict__ ws) {
    float* out_idx_f = out + OUT_IDX;
    float* zq        = out + OUT_ZQ;
    float* counts8   = ws + WS_C8;
    int*   acnt16    = (int*)(ws + WS_ACNT);
    float* loss_ws   = ws + WS_LOSS;
    float* embsum    = ws + WS_EMBSUM;
    float* enorm     = ws + WS_ENORM;
    int*   cursor8   = (int*)(ws + WS_CUR8);
    float* cs_ws     = ws + WS_CS;
    int*   ambig     = (int*)(ws + WS_AMBIG);
    int*   order     = (int*)(ws + WS_ORDER);
    int*   bar_cnt   = acnt16 + 8;
    int*   bar_gen   = acnt16 + 9;

    __shared__ int s_k[256];
    __shared__ int wtot[4];
    __shared__ float ftot[4];
    __shared__ float nsh;

    int tid = threadIdx.x;
    int bid = blockIdx.x;
    int gtid = bid * 256 + tid;
    int lane = tid & 63;
    int w = tid >> 6;

    // ------------- phase 0: exact fp32 rescue (R4 body, 2 rows/wave) -------------
    {
        int wave = gtid >> 6;
        int nw = gridDim.x * 4;
        int cnt = acnt16[0];
        for (int a = 2 * wave; a < cnt; a += 2 * nw) {
            int row0 = ambig[a];
            bool two = (a + 1) < cnt;
            int row1 = two ? ambig[a + 1] : row0;
            const float4* zp0 = (const float4*)(z + (size_t)row0 * DIM);
            const float4* zp1 = (const float4*)(z + (size_t)row1 * DIM);
            float4 zr0[16], zr1[16];
            float zn0 = 0.f, zn1 = 0.f;
#pragma unroll
            for (int i = 0; i < 16; ++i) {
                float4 u = zp0[i], v = zp1[i];
                zr0[i] = u; zr1[i] = v;
                zn0 += u.x * u.x + u.y * u.y + u.z * u.z + u.w * u.w;
                zn1 += v.x * v.x + v.y * v.y + v.z * v.z + v.w * v.w;
            }
            float best0 = INFINITY, best1 = INFINITY;
            int bi0 = 0, bi1 = 0;
            for (int j = 0; j < 16; ++j) {
                int code = j * 64 + lane;
                const float4* ep = (const float4*)(E + (size_t)code * DIM);
                float a0 = 0.f, a1 = 0.f, a2 = 0.f, a3 = 0.f;
                float c0 = 0.f, c1 = 0.f, c2 = 0.f, c3 = 0.f;
#pragma unroll
                for (int i = 0; i < 16; ++i) {
                    float4 ev = ep[i];
                    a0 += zr0[i].x * ev.x; a1 += zr0[i].y * ev.y;
                    a2 += zr0[i].z * ev.z; a3 += zr0[i].w * ev.w;
                    c0 += zr1[i].x * ev.x; c1 += zr1[i].y * ev.y;
                    c2 += zr1[i].z * ev.z; c3 += zr1[i].w * ev.w;
                }
                float en = enorm[code];
                float s0 = en - 2.f * ((a0 + a1) + (a2 + a3));
                float s1 = en - 2.f * ((c0 + c1) + (c2 + c3));
                if (s0 < best0) { best0 = s0; bi0 = code; }
                if (s1 < best1) { best1 = s1; bi1 = code; }
            }
#pragma unroll
            for (int off = 1; off < 64; off <<= 1) {
                float ob = __shfl_xor(best0, off);
                int oi = __shfl_xor(bi0, off);
                if (ob < best0 || (ob == best0 && oi < bi0)) { best0 = ob; bi0 = oi; }
                float ob1 = __shfl_xor(best1, off);
                int oi1 = __shfl_xor(bi1, off);
                if (ob1 < best1 || (ob1 == best1 && oi1 < bi1)) { best1 = ob1; bi1 = oi1; }
            }
            if (lane == 0) {
                out_idx_f[row0] = (float)bi0;
                atomicAdd(&counts8[(((unsigned)row0 >> 8) & 7) * K_CODES + bi0], 1.0f);
                float ladd = zn0 + best0;
                if (two) {
                    out_idx_f[row1] = (float)bi1;
                    atomicAdd(&counts8[(((unsigned)row1 >> 8) & 7) * K_CODES + bi1], 1.0f);
                    ladd += zn1 + best1;
                }
                atomicAdd(loss_ws, ladd);
            }
        }
    }
    gbar(bar_cnt, bar_gen, TAIL_BLKS);

    // ------------- phase 1: scan (block 0, 4 codes/thread) -------------
    if (bid == 0) {
        int wv = tid >> 6;
        float c8v[4][8];
        float ncs4[4];
        int tsum = 0; float fsum = 0.f;
#pragma unroll
        for (int u = 0; u < 4; ++u) {
            int kk = tid * 4 + u;
            float cnt = 0.f;
#pragma unroll
            for (int s = 0; s < 8; ++s) { c8v[u][s] = counts8[s * K_CODES + kk]; cnt += c8v[u][s]; }
            float ncs = cluster_size[kk] * DECAYF + OMDF * cnt;
            (out + OUT_NEWCS)[kk] = ncs;
            ncs4[u] = ncs;
            tsum += (int)cnt;
            fsum += ncs;
        }
        int vs = tsum;
#pragma unroll
        for (int off = 1; off < 64; off <<= 1) {
            int o = __shfl_up(vs, off, 64);
            if (lane >= off) vs += o;
        }
        float fs = fsum;
#pragma unroll
        for (int off = 1; off < 64; off <<= 1) fs += __shfl_xor(fs, off);
        if (lane == 63) wtot[wv] = vs;
        if (lane == 0) ftot[wv] = fs;
        __syncthreads();
        if (tid == 0) {
            int run = 0; float fn = 0.f;
#pragma unroll
            for (int i = 0; i < 4; ++i) { int x = wtot[i]; wtot[i] = run; run += x; fn += ftot[i]; }
            nsh = fn;
        }
        __syncthreads();
        float n = nsh;
        int run = (vs - tsum) + wtot[wv];
#pragma unroll
        for (int u = 0; u < 4; ++u) {
            int kk = tid * 4 + u;
            cs_ws[kk] = (ncs4[u] + EPSF) / (n + (float)K_CODES * EPSF) * n;
#pragma unroll
            for (int s = 0; s < 8; ++s) { cursor8[s * K_CODES + kk] = run; run += (int)c8v[u][s]; }
        }
    }
    gbar(bar_cnt, bar_gen, TAIL_BLKS);

    // ------------- phase 2: scatter order + z_q write (grid-stride) -------------
    for (int rb = bid; rb < N_PTS / 256; rb += gridDim.x) {
        int rbase = rb * 256;
        int row = rbase + tid;
        int k = (int)out_idx_f[row];
        s_k[tid] = k;
        int shard = ((unsigned)row >> 8) & 7;
        int p = atomicAdd(&cursor8[shard * K_CODES + k], 1);
        order[p] = (k << 17) | row;
        __syncthreads();
        size_t ebase = (size_t)rbase * DIM;
#pragma unroll 4
        for (int it = 0; it < 64; ++it) {
            int le = it * 256 + tid;
            int rl = le >> 6, d = le & 63;
            zq[ebase + le] = E[(size_t)s_k[rl] * DIM + d];
        }
        __syncthreads();
    }
    gbar(bar_cnt, bar_gen, TAIL_BLKS);

    // ------------- phase 3: segment sum (64 entries/wave, grid-stride) -------------
    for (int vb = bid; vb < N_PTS / 256; vb += gridDim.x) {
        int wave = vb * 4 + w;
        int base = wave * 64;
        int my = order[base + lane];
        int cur = __shfl(my, 0, 64) >> 17;
        float sum = 0.f;
#pragma unroll 8
        for (int i = 0; i < 64; ++i) {
            int p = __shfl(my, i, 64);
            int row = p & 0x1FFFF;
            int code = p >> 17;
            float v = z[(size_t)row * DIM + lane];
            if (code != cur) {
                atomicAdd(&embsum[(size_t)cur * DIM + lane], sum);
                sum = 0.f;
                cur = code;
            }
            sum += v;
        }
        atomicAdd(&embsum[(size_t)cur * DIM + lane], sum);
    }
    gbar(bar_cnt, bar_gen, TAIL_BLKS);

    // ------------- phase 4: EMA epilogue + loss finalize -------------
    for (int i = gtid; i < K_CODES * DIM; i += gridDim.x * 256) {
        float nes = ema[i] * DECAYF + OMDF * embsum[i];
        (out + OUT_NEWEMA)[i] = nes;
        (out + OUT_NEWEMB)[i] = nes / cs_ws[i >> 6];
    }
    if (gtid == 0)
        (out + OUT_LOSS)[0] = loss_ws[0] * (1.0f / ((float)N_PTS * (float)DIM));
}

extern "C" void kernel_launch(void* const* d_in, const int* in_sizes, int n_in,
                              void* d_out, int out_size, void* d_ws, size_t ws_size,
                              hipStream_t stream) {
    const float* z            = (const float*)d_in[0];
    const float* E            = (const float*)d_in[1];
    const float* cluster_size = (const float*)d_in[2];
    const float* ema          = (const float*)d_in[3];
    float* out = (float*)d_out;
    float* ws  = (float*)d_ws;

    econv_kernel<<<K_CODES / 64, 256, 0, stream>>>(E, ws);

    argmin_mfma<<<N_PTS / 256, 256, 0, stream>>>(z, (const short*)(ws + WS_E2S),
                                                 out + OUT_IDX,
                                                 ws + WS_C8,
                                                 (int*)(ws + WS_ACNT),
                                                 (int*)(ws + WS_AMBIG),
                                                 ws + WS_LOSS);

    vq_tail<<<TAIL_BLKS, 256, 0, stream>>>(z, E, cluster_size, ema, out, ws);
}

// Round 8
// 247.602 us; speedup vs baseline: 1.2961x; 1.2961x over previous
//
#include <hip/hip_runtime.h>

#define N_PTS 131072
#define K_CODES 1024
#define DIM 64
#define DECAYF 0.99f
#define OMDF 0.01f
#define EPSF 1e-5f

// ---- d_out layout (float elements, reference return order) ----
#define OUT_ZQ      0                  // [N, D]
#define OUT_LOSS    8388608            // scalar
#define OUT_IDX     8388609            // [N] (indices as floats)
#define OUT_NEWEMB  8519681            // [K, D]
#define OUT_NEWCS   8585217            // [K]
#define OUT_NEWEMA  8586241            // [K, D]

// ---- ws layout (float elements) ----
// zero region: [0, WS_ZERO_END) — zeroed by econv's grid-stride loop
#define WS_C8       0                  // 8*K floats
#define WS_ACNT     8192               // 16 ints: [0]=ambig_cnt
#define WS_LOSS     8208               // 16 floats
#define WS_EMBSUM   8224               // K*D floats (atomic accumulator)
#define WS_ZERO_END 73760
#define WS_ENORM    73760              // K
#define WS_CS       82976              // K
#define WS_AMBIG    84000              // N ints
// E2S: staged-layout B operand (66560 floats). Lives in the region the old
// ORDER array used; consumed only by the argmin dispatch.
#define WS_E2S      215072

// E2S step layout (bytes, per step s of 64 codes = 4 tiles):
//   [0,16384): B frags, short addr = tau*2048 + p*512 + q*128 + c*8
//   [16384,16640): enorm[tau*16+c] as float
#define STEP_BYTES  16640
#define STEP_SHORTS 8320
#define STEP_FLOATS 4160

typedef __attribute__((ext_vector_type(8))) short bf16x8;
typedef __attribute__((ext_vector_type(4))) float f32x4;

static __device__ inline short f2bf(float f) {
    unsigned u = __float_as_uint(f);
    unsigned r = (u + 0x7fffu + ((u >> 16) & 1u)) >> 16;   // RNE
    return (short)r;
}
static __device__ inline float bf2f(short h) {
    return __uint_as_float(((unsigned)(unsigned short)h) << 16);
}

static __device__ __forceinline__ void gload16(const char* g, char* l) {
    __builtin_amdgcn_global_load_lds(
        (const __attribute__((address_space(1))) void*)g,
        (__attribute__((address_space(3))) void*)l, 16, 0, 0);
}
static __device__ __forceinline__ void gload4(const char* g, char* l) {
    __builtin_amdgcn_global_load_lds(
        (const __attribute__((address_space(1))) void*)g,
        (__attribute__((address_space(3))) void*)l, 4, 0, 0);
}

// Zero the ws accumulator region + E -> E2S (staged layout of bf16 hi/lo
// split of -2E, plus per-step enorm tail) + global enorm fp32 (for rescue).
// 4 threads per code. (R7-proven body.)
__global__ __launch_bounds__(256) void econv_kernel(const float* __restrict__ E,
                                                    float* __restrict__ ws) {
    int tid = threadIdx.x;
    int gid = blockIdx.x * 256 + tid;
    // zero accumulators (counts8, ambig_cnt, loss, embsum)
    for (int i = gid; i < WS_ZERO_END; i += 16 * 256) ws[i] = 0.f;

    short* E2S = (short*)(ws + WS_E2S);
    float* enorm = ws + WS_ENORM;
    int code = blockIdx.x * 64 + (tid >> 2);
    int seg = tid & 3;
    const float4* e4 = (const float4*)(E + (size_t)code * DIM + seg * 16);
    float4 v0 = e4[0], v1 = e4[1], v2 = e4[2], v3 = e4[3];
    float f[16];
    f[0]=v0.x; f[1]=v0.y; f[2]=v0.z; f[3]=v0.w;
    f[4]=v1.x; f[5]=v1.y; f[6]=v1.z; f[7]=v1.w;
    f[8]=v2.x; f[9]=v2.y; f[10]=v2.z; f[11]=v2.w;
    f[12]=v3.x; f[13]=v3.y; f[14]=v3.z; f[15]=v3.w;
    float s = 0.f;
#pragma unroll
    for (int j = 0; j < 16; ++j) s += f[j] * f[j];
    s += __shfl_xor(s, 1);
    s += __shfl_xor(s, 2);
    short hi[16], lo[16];
#pragma unroll
    for (int j = 0; j < 16; ++j) {
        float m = -2.f * f[j];
        short h = f2bf(m);
        hi[j] = h;
        lo[j] = f2bf(m - bf2f(h));
    }
    int sstep = code >> 6;
    int tau = (code >> 4) & 3;
    int cc = code & 15;
    size_t stepb = (size_t)sstep * STEP_SHORTS;
    int p_hi = seg >> 1, p_lo = 2 + (seg >> 1);
#pragma unroll
    for (int h8 = 0; h8 < 2; ++h8) {
        int qq = ((seg & 1) << 1) | h8;
        size_t base = stepb + tau * 2048 + qq * 128 + cc * 8;
        bf16x8 vh, vl;
#pragma unroll
        for (int j = 0; j < 8; ++j) { vh[j] = hi[h8 * 8 + j]; vl[j] = lo[h8 * 8 + j]; }
        *(bf16x8*)(E2S + base + p_hi * 512) = vh;
        *(bf16x8*)(E2S + base + p_lo * 512) = vl;
    }
    if (seg == 0) {
        ((float*)E2S)[(size_t)sstep * STEP_FLOATS + 4096 + tau * 16 + cc] = s;
        enorm[code] = s;
    }
}

// 512 blocks x 256 thr; wave = 64 rows (4 m-tiles) x all 1024 codes.
// B operand double-buffer-staged in LDS per BLOCK (proven R4 form, 71us).
__global__ __launch_bounds__(256) void argmin_mfma(const float* __restrict__ z,
                                                   const short* __restrict__ E2S,
                                                   float* __restrict__ out_idx_f,
                                                   float* __restrict__ counts8,
                                                   int* __restrict__ ambig_cnt,
                                                   int* __restrict__ ambig,
                                                   float* __restrict__ loss_ws) {
    int tid = threadIdx.x;
    int w = tid >> 6, lane = tid & 63;
    int c = lane & 15, q = lane >> 4;
    int mbase = blockIdx.x * 256 + w * 64;

    __shared__ char smem[2 * STEP_BYTES] __attribute__((aligned(16)));
    const char* E2Sc = (const char*)E2S;

#define STAGE(SBUF, SSTEP) do {                                               \
    const char* g_ = E2Sc + (size_t)(SSTEP) * STEP_BYTES + w * 1024 + lane * 16; \
    char* l_ = smem + (SBUF) * STEP_BYTES + w * 1024;                         \
    gload16(g_,          l_);                                                 \
    gload16(g_ + 4096,   l_ + 4096);                                          \
    gload16(g_ + 8192,   l_ + 8192);                                          \
    gload16(g_ + 12288,  l_ + 12288);                                         \
    if (w == 0)                                                               \
        gload4(E2Sc + (size_t)(SSTEP) * STEP_BYTES + 16384 + lane * 4,        \
               smem + (SBUF) * STEP_BYTES + 16384);                           \
} while (0)

    // issue step-0 staging first; A-prep global loads hide its latency
    STAGE(0, 0);

    bf16x8 a[4][4];   // [t][p]: p= 0:hi d0-31, 1:hi d32-63, 2:lo d0-31, 3:lo d32-63
    float znorm_t[4];
#pragma unroll
    for (int t = 0; t < 4; ++t) {
        const float* zp = z + (size_t)(mbase + t * 16 + c) * DIM;
        const float4* z4a = (const float4*)(zp + q * 8);
        const float4* z4b = (const float4*)(zp + 32 + q * 8);
        float f[16];
        float4 v0 = z4a[0], v1 = z4a[1], v2 = z4b[0], v3 = z4b[1];
        f[0]=v0.x; f[1]=v0.y; f[2]=v0.z; f[3]=v0.w;
        f[4]=v1.x; f[5]=v1.y; f[6]=v1.z; f[7]=v1.w;
        f[8]=v2.x; f[9]=v2.y; f[10]=v2.z; f[11]=v2.w;
        f[12]=v3.x; f[13]=v3.y; f[14]=v3.z; f[15]=v3.w;
        float zn = 0.f;
#pragma unroll
        for (int j = 0; j < 16; ++j) zn += f[j] * f[j];
#pragma unroll
        for (int off = 16; off < 64; off <<= 1) zn += __shfl_xor(zn, off);
        znorm_t[t] = zn;
#pragma unroll
        for (int j = 0; j < 8; ++j) {
            short h0 = f2bf(f[j]);
            a[t][0][j] = h0;
            a[t][2][j] = f2bf(f[j] - bf2f(h0));
            short h1 = f2bf(f[8 + j]);
            a[t][1][j] = h1;
            a[t][3][j] = f2bf(f[8 + j] - bf2f(h1));
        }
    }

    float s1[16], s2[16];
#pragma unroll
    for (int idx = 0; idx < 16; ++idx) { s1[idx] = INFINITY; s2[idx] = INFINITY; }

    __syncthreads();   // step-0 staging drained (vmcnt 0 before barrier)

    int bfr = (q << 4) + c;   // B frag unit index within a p-block
    for (int st = 0; st < 16; ++st) {
        if (st < 15) STAGE((st + 1) & 1, st + 1);
        const short* lb = (const short*)(smem + (st & 1) * STEP_BYTES);
        const float* lef = (const float*)(smem + (st & 1) * STEP_BYTES + 16384);
#pragma unroll
        for (int tau = 0; tau < 4; ++tau) {
            const bf16x8* bp = (const bf16x8*)lb + tau * 256 + bfr;
            bf16x8 bh0 = bp[0], bh1 = bp[64], bl0 = bp[128], bl1 = bp[192];
            float en = lef[tau * 16 + c];
            unsigned vcode = (unsigned)((((st << 2) + tau) << 4) | c);
#pragma unroll
            for (int t = 0; t < 4; ++t) {
                f32x4 acc = {en, en, en, en};
                acc = __builtin_amdgcn_mfma_f32_16x16x32_bf16(a[t][0], bl0, acc, 0, 0, 0);
                acc = __builtin_amdgcn_mfma_f32_16x16x32_bf16(a[t][1], bl1, acc, 0, 0, 0);
                acc = __builtin_amdgcn_mfma_f32_16x16x32_bf16(a[t][2], bh0, acc, 0, 0, 0);
                acc = __builtin_amdgcn_mfma_f32_16x16x32_bf16(a[t][3], bh1, acc, 0, 0, 0);
                acc = __builtin_amdgcn_mfma_f32_16x16x32_bf16(a[t][0], bh0, acc, 0, 0, 0);
                acc = __builtin_amdgcn_mfma_f32_16x16x32_bf16(a[t][1], bh1, acc, 0, 0, 0);
#pragma unroll
                for (int i = 0; i < 4; ++i) {
                    float sp = __uint_as_float(
                        (__float_as_uint(acc[i]) & 0xFFFFFC00u) | vcode);
                    int idx = t * 4 + i;
                    float ns2 = __builtin_amdgcn_fmed3f(s1[idx], s2[idx], sp);
                    s1[idx] = fminf(s1[idx], sp);
                    s2[idx] = ns2;
                }
            }
        }
        __syncthreads();
    }
#undef STAGE

#pragma unroll
    for (int off = 1; off < 16; off <<= 1) {
#pragma unroll
        for (int idx = 0; idx < 16; ++idx) {
            float os1 = __shfl_xor(s1[idx], off);
            float os2 = __shfl_xor(s2[idx], off);
            float ns1 = fminf(s1[idx], os1);
            s2[idx] = fminf(fmaxf(s1[idx], os1), fminf(s2[idx], os2));
            s1[idx] = ns1;
        }
    }

    float znr[16];
#pragma unroll
    for (int t = 0; t < 4; ++t)
#pragma unroll
        for (int i = 0; i < 4; ++i)
            znr[t * 4 + i] = __shfl(znorm_t[t], (q << 4) | (q * 4 + i), 64);

    float* lred = (float*)smem;   // staging buffers dead after loop
    float lsum = 0.f;
    if (c == 0) {
#pragma unroll
        for (int idx = 0; idx < 16; ++idx) {
            int t = idx >> 2, i = idx & 3;
            int row = mbase + t * 16 + q * 4 + i;
            unsigned b1 = __float_as_uint(s1[idx]);
            int code = (int)(b1 & 1023u);
            out_idx_f[row] = (float)code;
            float s1v = __uint_as_float(b1 & 0xFFFFFC00u);
            float gap = s2[idx] - s1[idx];
            float tau = 0.008f + 8e-4f * (fabsf(s1[idx]) + fabsf(s2[idx]));
            if (gap >= tau) {
                atomicAdd(&counts8[(((unsigned)row >> 8) & 7) * K_CODES + code], 1.0f);
                lsum += znr[idx] + s1v;
            } else {
                int p = atomicAdd(ambig_cnt, 1);
                ambig[p] = row;
            }
        }
        lred[w * 4 + q] = lsum;
    }
    __syncthreads();
    if (tid == 0) {
        float tot = 0.f;
#pragma unroll
        for (int i = 0; i < 16; ++i) tot += lred[i];
        atomicAdd(loss_ws, tot);
    }
}

// Wave per 2 ambiguous rows: exact fp32 rescore over all K codes; also adds
// the exact loss contribution for those rows. R4 body VERBATIM (razor-tie
// rows are decided by this exact compiled rounding — do not re-derive).
__global__ __launch_bounds__(256) void rescue_kernel(const float* __restrict__ z,
                                                     const float* __restrict__ E,
                                                     const float* __restrict__ enorm,
                                                     const int* __restrict__ ambig_cnt,
                                                     const int* __restrict__ ambig,
                                                     float* __restrict__ out_idx_f,
                                                     float* __restrict__ counts8,
                                                     float* __restrict__ loss_ws) {
    int lane = threadIdx.x & 63;
    int wave = (blockIdx.x * 256 + threadIdx.x) >> 6;
    int nw = gridDim.x * 4;
    int cnt = *ambig_cnt;
    for (int a = 2 * wave; a < cnt; a += 2 * nw) {
        int row0 = ambig[a];
        bool two = (a + 1) < cnt;
        int row1 = two ? ambig[a + 1] : row0;
        const float4* zp0 = (const float4*)(z + (size_t)row0 * DIM);
        const float4* zp1 = (const float4*)(z + (size_t)row1 * DIM);
        float4 zr0[16], zr1[16];
        float zn0 = 0.f, zn1 = 0.f;
#pragma unroll
        for (int i = 0; i < 16; ++i) {
            float4 u = zp0[i], v = zp1[i];
            zr0[i] = u; zr1[i] = v;
            zn0 += u.x * u.x + u.y * u.y + u.z * u.z + u.w * u.w;
            zn1 += v.x * v.x + v.y * v.y + v.z * v.z + v.w * v.w;
        }
        float best0 = INFINITY, best1 = INFINITY;
        int bi0 = 0, bi1 = 0;
        for (int j = 0; j < 16; ++j) {
            int code = j * 64 + lane;
            const float4* ep = (const float4*)(E + (size_t)code * DIM);
            float a0 = 0.f, a1 = 0.f, a2 = 0.f, a3 = 0.f;
            float c0 = 0.f, c1 = 0.f, c2 = 0.f, c3 = 0.f;
#pragma unroll
            for (int i = 0; i < 16; ++i) {
                float4 ev = ep[i];
                a0 += zr0[i].x * ev.x; a1 += zr0[i].y * ev.y;
                a2 += zr0[i].z * ev.z; a3 += zr0[i].w * ev.w;
                c0 += zr1[i].x * ev.x; c1 += zr1[i].y * ev.y;
                c2 += zr1[i].z * ev.z; c3 += zr1[i].w * ev.w;
            }
            float en = enorm[code];
            float s0 = en - 2.f * ((a0 + a1) + (a2 + a3));
            float s1 = en - 2.f * ((c0 + c1) + (c2 + c3));
            if (s0 < best0) { best0 = s0; bi0 = code; }
            if (s1 < best1) { best1 = s1; bi1 = code; }
        }
#pragma unroll
        for (int off = 1; off < 64; off <<= 1) {
            float ob = __shfl_xor(best0, off);
            int oi = __shfl_xor(bi0, off);
            if (ob < best0 || (ob == best0 && oi < bi0)) { best0 = ob; bi0 = oi; }
            float ob1 = __shfl_xor(best1, off);
            int oi1 = __shfl_xor(bi1, off);
            if (ob1 < best1 || (ob1 == best1 && oi1 < bi1)) { best1 = ob1; bi1 = oi1; }
        }
        if (lane == 0) {
            out_idx_f[row0] = (float)bi0;
            atomicAdd(&counts8[(((unsigned)row0 >> 8) & 7) * K_CODES + bi0], 1.0f);
            float ladd = zn0 + best0;
            if (two) {
                out_idx_f[row1] = (float)bi1;
                atomicAdd(&counts8[(((unsigned)row1 >> 8) & 7) * K_CODES + bi1], 1.0f);
                ladd += zn1 + best1;
            }
            atomicAdd(loss_ws, ladd);
        }
    }
}

// Fused z_q write + DIRECT-ATOMIC embed_sum (replaces scan-cursors/scatter/
// order/segsum: the sort existed to cut atomic contention, but 131072
// 256B-adds over 1024 code-lines is only ~128 serialized ops/line — ~1-2us
// in L2/L3). z read here is fully coalesced (segsum's was gathered).
// Blocks 0..2047: 64 rows each. Block 2048: the ncs/cs scan (independent
// of idx — only needs rescue-final counts8).
__global__ __launch_bounds__(256) void zq_embsum_kernel(const float* __restrict__ z,
                                                        const float* __restrict__ E,
                                                        const float* __restrict__ idx_f,
                                                        const float* __restrict__ cluster_size,
                                                        const float* __restrict__ counts8,
                                                        float* __restrict__ ncs_out,
                                                        float* __restrict__ cs_ws,
                                                        float* __restrict__ embsum,
                                                        float* __restrict__ zq) {
    __shared__ int s_k[64];
    __shared__ float ftot[4];
    __shared__ float nsh;

    int tid = threadIdx.x;
    int bid = blockIdx.x;
    int lane = tid & 63;
    int w = tid >> 6;

    if (bid == 2048) {
        // ncs, n, cs (no cursors needed anymore). 4 codes/thread.
        float ncs4[4];
        float fsum = 0.f;
#pragma unroll
        for (int u = 0; u < 4; ++u) {
            int kk = tid * 4 + u;
            float cnt = 0.f;
#pragma unroll
            for (int s = 0; s < 8; ++s) cnt += counts8[s * K_CODES + kk];
            float ncs = cluster_size[kk] * DECAYF + OMDF * cnt;
            ncs_out[kk] = ncs;
            ncs4[u] = ncs;
            fsum += ncs;
        }
#pragma unroll
        for (int off = 1; off < 64; off <<= 1) fsum += __shfl_xor(fsum, off);
        if (lane == 0) ftot[w] = fsum;
        __syncthreads();
        if (tid == 0) nsh = ftot[0] + ftot[1] + ftot[2] + ftot[3];
        __syncthreads();
        float n = nsh;
#pragma unroll
        for (int u = 0; u < 4; ++u) {
            int kk = tid * 4 + u;
            cs_ws[kk] = (ncs4[u] + EPSF) / (n + (float)K_CODES * EPSF) * n;
        }
        return;
    }

    int rbase = bid * 64;
    if (tid < 64) s_k[tid] = (int)idx_f[rbase + tid];
    __syncthreads();

#pragma unroll 4
    for (int r = w; r < 64; r += 4) {
        int row = rbase + r;
        int k = s_k[r];
        float zv = z[(size_t)row * DIM + lane];
        atomicAdd(&embsum[(size_t)k * DIM + lane], zv);
        zq[(size_t)row * DIM + lane] = E[(size_t)k * DIM + lane];
    }
}

// EMA epilogue over [K, D] + loss finalize (R4 body).
__global__ __launch_bounds__(256) void ema2_kernel(const float* __restrict__ ema,
                                                   const float* __restrict__ embsum,
                                                   const float* __restrict__ cs_ws,
                                                   const float* __restrict__ loss_ws,
                                                   float* __restrict__ newema_out,
                                                   float* __restrict__ newemb_out,
                                                   float* __restrict__ loss_out) {
    int i = blockIdx.x * 256 + threadIdx.x;
    float nes = ema[i] * DECAYF + OMDF * embsum[i];
    newema_out[i] = nes;
    newemb_out[i] = nes / cs_ws[i >> 6];
    if (i == 0)
        loss_out[0] = loss_ws[0] * (1.0f / ((float)N_PTS * (float)DIM));
}

extern "C" void kernel_launch(void* const* d_in, const int* in_sizes, int n_in,
                              void* d_out, int out_size, void* d_ws, size_t ws_size,
                              hipStream_t stream) {
    const float* z            = (const float*)d_in[0];
    const float* E            = (const float*)d_in[1];
    const float* cluster_size = (const float*)d_in[2];
    const float* ema          = (const float*)d_in[3];
    float* out = (float*)d_out;
    float* ws  = (float*)d_ws;

    econv_kernel<<<K_CODES / 64, 256, 0, stream>>>(E, ws);

    argmin_mfma<<<N_PTS / 256, 256, 0, stream>>>(z, (const short*)(ws + WS_E2S),
                                                 out + OUT_IDX,
                                                 ws + WS_C8,
                                                 (int*)(ws + WS_ACNT),
                                                 (int*)(ws + WS_AMBIG),
                                                 ws + WS_LOSS);

    rescue_kernel<<<512, 256, 0, stream>>>(z, E, ws + WS_ENORM,
                                           (const int*)(ws + WS_ACNT),
                                           (const int*)(ws + WS_AMBIG),
                                           out + OUT_IDX,
                                           ws + WS_C8,
                                           ws + WS_LOSS);

    zq_embsum_kernel<<<N_PTS / 64 + 1, 256, 0, stream>>>(z, E, out + OUT_IDX,
                                                         cluster_size,
                                                         ws + WS_C8,
                                                         out + OUT_NEWCS,
                                                         ws + WS_CS,
                                                         ws + WS_EMBSUM,
                                                         out + OUT_ZQ);

    ema2_kernel<<<K_CODES * DIM / 256, 256, 0, stream>>>(ema, ws + WS_EMBSUM,
                                                         ws + WS_CS,
                                                         ws + WS_LOSS,
                                                         out + OUT_NEWEMA,
                                                         out + OUT_NEWEMB,
                                                         out + OUT_LOSS);
}

// Round 9
// 216.427 us; speedup vs baseline: 1.4828x; 1.1440x over previous
//
#include <hip/hip_runtime.h>

#define N_PTS 131072
#define K_CODES 1024
#define DIM 64
#define DECAYF 0.99f
#define OMDF 0.01f
#define EPSF 1e-5f

// ---- d_out layout (float elements, reference return order) ----
#define OUT_ZQ      0                  // [N, D]
#define OUT_LOSS    8388608            // scalar
#define OUT_IDX     8388609            // [N] (indices as floats)
#define OUT_NEWEMB  8519681            // [K, D]
#define OUT_NEWCS   8585217            // [K]
#define OUT_NEWEMA  8586241            // [K, D]

// ---- ws layout (float elements) ----
// zero region: [0, WS_ZERO_END) — zeroed by econv's grid-stride loop
#define WS_C8       0                  // 8*K floats
#define WS_ACNT     8192               // 16 ints: [0]=ambig_cnt
#define WS_LOSS     8208               // 16 floats
#define WS_EMBSUM   8224               // K*D floats (atomic accumulator)
#define WS_ZERO_END 73760
#define WS_ENORM    73760              // K
#define WS_CUR8     74784              // 8*K ints
#define WS_CS       82976              // K
#define WS_AMBIG    84000              // N ints
#define WS_ORDER    215072             // N ints (packed code<<17|row)
// E2S aliases ORDER: E2S consumed by the argmin dispatch; ORDER written by
// the later scatter dispatch — disjoint in time across dispatch boundaries.
#define WS_E2S      215072

// E2S step layout (bytes, per step s of 64 codes = 4 tiles):
//   [0,16384): B frags, short addr = tau*2048 + p*512 + q*128 + c*8
//   [16384,16640): enorm[tau*16+c] as float
#define STEP_BYTES  16640
#define STEP_SHORTS 8320
#define STEP_FLOATS 4160

typedef __attribute__((ext_vector_type(8))) short bf16x8;
typedef __attribute__((ext_vector_type(4))) float f32x4;

static __device__ inline short f2bf(float f) {
    unsigned u = __float_as_uint(f);
    unsigned r = (u + 0x7fffu + ((u >> 16) & 1u)) >> 16;   // RNE
    return (short)r;
}
static __device__ inline float bf2f(short h) {
    return __uint_as_float(((unsigned)(unsigned short)h) << 16);
}

static __device__ __forceinline__ void gload16(const char* g, char* l) {
    __builtin_amdgcn_global_load_lds(
        (const __attribute__((address_space(1))) void*)g,
        (__attribute__((address_space(3))) void*)l, 16, 0, 0);
}
static __device__ __forceinline__ void gload4(const char* g, char* l) {
    __builtin_amdgcn_global_load_lds(
        (const __attribute__((address_space(1))) void*)g,
        (__attribute__((address_space(3))) void*)l, 4, 0, 0);
}

// Zero the ws accumulator region + E -> E2S (staged layout of bf16 hi/lo
// split of -2E, plus per-step enorm tail) + global enorm fp32 (for rescue).
// 4 threads per code. (R7/R8-proven body.)
__global__ __launch_bounds__(256) void econv_kernel(const float* __restrict__ E,
                                                    float* __restrict__ ws) {
    int tid = threadIdx.x;
    int gid = blockIdx.x * 256 + tid;
    // zero accumulators (counts8, ambig_cnt, loss, embsum)
    for (int i = gid; i < WS_ZERO_END; i += 16 * 256) ws[i] = 0.f;

    short* E2S = (short*)(ws + WS_E2S);
    float* enorm = ws + WS_ENORM;
    int code = blockIdx.x * 64 + (tid >> 2);
    int seg = tid & 3;
    const float4* e4 = (const float4*)(E + (size_t)code * DIM + seg * 16);
    float4 v0 = e4[0], v1 = e4[1], v2 = e4[2], v3 = e4[3];
    float f[16];
    f[0]=v0.x; f[1]=v0.y; f[2]=v0.z; f[3]=v0.w;
    f[4]=v1.x; f[5]=v1.y; f[6]=v1.z; f[7]=v1.w;
    f[8]=v2.x; f[9]=v2.y; f[10]=v2.z; f[11]=v2.w;
    f[12]=v3.x; f[13]=v3.y; f[14]=v3.z; f[15]=v3.w;
    float s = 0.f;
#pragma unroll
    for (int j = 0; j < 16; ++j) s += f[j] * f[j];
    s += __shfl_xor(s, 1);
    s += __shfl_xor(s, 2);
    short hi[16], lo[16];
#pragma unroll
    for (int j = 0; j < 16; ++j) {
        float m = -2.f * f[j];
        short h = f2bf(m);
        hi[j] = h;
        lo[j] = f2bf(m - bf2f(h));
    }
    int sstep = code >> 6;
    int tau = (code >> 4) & 3;
    int cc = code & 15;
    size_t stepb = (size_t)sstep * STEP_SHORTS;
    int p_hi = seg >> 1, p_lo = 2 + (seg >> 1);
#pragma unroll
    for (int h8 = 0; h8 < 2; ++h8) {
        int qq = ((seg & 1) << 1) | h8;
        size_t base = stepb + tau * 2048 + qq * 128 + cc * 8;
        bf16x8 vh, vl;
#pragma unroll
        for (int j = 0; j < 8; ++j) { vh[j] = hi[h8 * 8 + j]; vl[j] = lo[h8 * 8 + j]; }
        *(bf16x8*)(E2S + base + p_hi * 512) = vh;
        *(bf16x8*)(E2S + base + p_lo * 512) = vl;
    }
    if (seg == 0) {
        ((float*)E2S)[(size_t)sstep * STEP_FLOATS + 4096 + tau * 16 + cc] = s;
        enorm[code] = s;
    }
}

// 1024 blocks x 256 thr; wave = 32 rows (2 m-tiles) x all 1024 codes.
// B operand LDS-staged per BLOCK (so doubling blocks does NOT double the
// per-wave B stream — only L2 staging traffic, +4us). vs the R4 t=4 form:
// same per-row FP (bit-identical codes, no razor-tie re-roll), half the
// rows/wave, 4 blocks/CU (LDS 33KB x4 = 132 <= 160KB) -> 2x occupancy on
// a kernel that was 17% occupancy with both pipes < 50%.
__global__ __launch_bounds__(256) void argmin_mfma(const float* __restrict__ z,
                                                   const short* __restrict__ E2S,
                                                   float* __restrict__ out_idx_f,
                                                   float* __restrict__ counts8,
                                                   int* __restrict__ ambig_cnt,
                                                   int* __restrict__ ambig,
                                                   float* __restrict__ loss_ws) {
    int tid = threadIdx.x;
    int w = tid >> 6, lane = tid & 63;
    int c = lane & 15, q = lane >> 4;
    int mbase = blockIdx.x * 128 + w * 32;

    __shared__ char smem[2 * STEP_BYTES] __attribute__((aligned(16)));
    const char* E2Sc = (const char*)E2S;

#define STAGE(SBUF, SSTEP) do {                                               \
    const char* g_ = E2Sc + (size_t)(SSTEP) * STEP_BYTES + w * 1024 + lane * 16; \
    char* l_ = smem + (SBUF) * STEP_BYTES + w * 1024;                         \
    gload16(g_,          l_);                                                 \
    gload16(g_ + 4096,   l_ + 4096);                                          \
    gload16(g_ + 8192,   l_ + 8192);                                          \
    gload16(g_ + 12288,  l_ + 12288);                                         \
    if (w == 0)                                                               \
        gload4(E2Sc + (size_t)(SSTEP) * STEP_BYTES + 16384 + lane * 4,        \
               smem + (SBUF) * STEP_BYTES + 16384);                           \
} while (0)

    // issue step-0 staging first; A-prep global loads hide its latency
    STAGE(0, 0);

    bf16x8 a[2][4];   // [t][p]: p= 0:hi d0-31, 1:hi d32-63, 2:lo d0-31, 3:lo d32-63
    float znorm_t[2];
#pragma unroll
    for (int t = 0; t < 2; ++t) {
        const float* zp = z + (size_t)(mbase + t * 16 + c) * DIM;
        const float4* z4a = (const float4*)(zp + q * 8);
        const float4* z4b = (const float4*)(zp + 32 + q * 8);
        float f[16];
        float4 v0 = z4a[0], v1 = z4a[1], v2 = z4b[0], v3 = z4b[1];
        f[0]=v0.x; f[1]=v0.y; f[2]=v0.z; f[3]=v0.w;
        f[4]=v1.x; f[5]=v1.y; f[6]=v1.z; f[7]=v1.w;
        f[8]=v2.x; f[9]=v2.y; f[10]=v2.z; f[11]=v2.w;
        f[12]=v3.x; f[13]=v3.y; f[14]=v3.z; f[15]=v3.w;
        float zn = 0.f;
#pragma unroll
        for (int j = 0; j < 16; ++j) zn += f[j] * f[j];
#pragma unroll
        for (int off = 16; off < 64; off <<= 1) zn += __shfl_xor(zn, off);
        znorm_t[t] = zn;
#pragma unroll
        for (int j = 0; j < 8; ++j) {
            short h0 = f2bf(f[j]);
            a[t][0][j] = h0;
            a[t][2][j] = f2bf(f[j] - bf2f(h0));
            short h1 = f2bf(f[8 + j]);
            a[t][1][j] = h1;
            a[t][3][j] = f2bf(f[8 + j] - bf2f(h1));
        }
    }

    float s1[8], s2[8];
#pragma unroll
    for (int idx = 0; idx < 8; ++idx) { s1[idx] = INFINITY; s2[idx] = INFINITY; }

    __syncthreads();   // step-0 staging drained (vmcnt 0 before barrier)

    int bfr = (q << 4) + c;   // B frag unit index within a p-block
    for (int st = 0; st < 16; ++st) {
        if (st < 15) STAGE((st + 1) & 1, st + 1);
        const short* lb = (const short*)(smem + (st & 1) * STEP_BYTES);
        const float* lef = (const float*)(smem + (st & 1) * STEP_BYTES + 16384);
#pragma unroll
        for (int tau = 0; tau < 4; ++tau) {
            const bf16x8* bp = (const bf16x8*)lb + tau * 256 + bfr;
            bf16x8 bh0 = bp[0], bh1 = bp[64], bl0 = bp[128], bl1 = bp[192];
            float en = lef[tau * 16 + c];
            unsigned vcode = (unsigned)((((st << 2) + tau) << 4) | c);
#pragma unroll
            for (int t = 0; t < 2; ++t) {
                f32x4 acc = {en, en, en, en};
                acc = __builtin_amdgcn_mfma_f32_16x16x32_bf16(a[t][0], bl0, acc, 0, 0, 0);
                acc = __builtin_amdgcn_mfma_f32_16x16x32_bf16(a[t][1], bl1, acc, 0, 0, 0);
                acc = __builtin_amdgcn_mfma_f32_16x16x32_bf16(a[t][2], bh0, acc, 0, 0, 0);
                acc = __builtin_amdgcn_mfma_f32_16x16x32_bf16(a[t][3], bh1, acc, 0, 0, 0);
                acc = __builtin_amdgcn_mfma_f32_16x16x32_bf16(a[t][0], bh0, acc, 0, 0, 0);
                acc = __builtin_amdgcn_mfma_f32_16x16x32_bf16(a[t][1], bh1, acc, 0, 0, 0);
#pragma unroll
                for (int i = 0; i < 4; ++i) {
                    float sp = __uint_as_float(
                        (__float_as_uint(acc[i]) & 0xFFFFFC00u) | vcode);
                    int idx = t * 4 + i;
                    float ns2 = __builtin_amdgcn_fmed3f(s1[idx], s2[idx], sp);
                    s1[idx] = fminf(s1[idx], sp);
                    s2[idx] = ns2;
                }
            }
        }
        __syncthreads();
    }
#undef STAGE

#pragma unroll
    for (int off = 1; off < 16; off <<= 1) {
#pragma unroll
        for (int idx = 0; idx < 8; ++idx) {
            float os1 = __shfl_xor(s1[idx], off);
            float os2 = __shfl_xor(s2[idx], off);
            float ns1 = fminf(s1[idx], os1);
            s2[idx] = fminf(fmaxf(s1[idx], os1), fminf(s2[idx], os2));
            s1[idx] = ns1;
        }
    }

    // znorm transport: lane (q*16 + r) holds znorm for row mbase + t*16 + r
    float znr[8];
#pragma unroll
    for (int t = 0; t < 2; ++t)
#pragma unroll
        for (int i = 0; i < 4; ++i)
            znr[t * 4 + i] = __shfl(znorm_t[t], (q << 4) | (q * 4 + i), 64);

    float* lred = (float*)smem;   // staging buffers dead after loop
    float lsum = 0.f;
    if (c == 0) {
#pragma unroll
        for (int idx = 0; idx < 8; ++idx) {
            int t = idx >> 2, i = idx & 3;
            int row = mbase + t * 16 + q * 4 + i;
            unsigned b1 = __float_as_uint(s1[idx]);
            int code = (int)(b1 & 1023u);
            out_idx_f[row] = (float)code;
            float s1v = __uint_as_float(b1 & 0xFFFFFC00u);
            float gap = s2[idx] - s1[idx];
            float tau = 0.008f + 8e-4f * (fabsf(s1[idx]) + fabsf(s2[idx]));
            if (gap >= tau) {
                atomicAdd(&counts8[(((unsigned)row >> 8) & 7) * K_CODES + code], 1.0f);
                lsum += znr[idx] + s1v;
            } else {
                int p = atomicAdd(ambig_cnt, 1);
                ambig[p] = row;
            }
        }
        lred[w * 4 + q] = lsum;
    }
    __syncthreads();
    if (tid == 0) {
        float tot = 0.f;
#pragma unroll
        for (int i = 0; i < 16; ++i) tot += lred[i];
        atomicAdd(loss_ws, tot);
    }
}

// Wave per 2 ambiguous rows: exact fp32 rescore over all K codes; also adds
// the exact loss contribution for those rows. R4 body VERBATIM (razor-tie
// rows are decided by this exact compiled rounding — do not re-derive).
__global__ __launch_bounds__(256) void rescue_kernel(const float* __restrict__ z,
                                                     const float* __restrict__ E,
                                                     const float* __restrict__ enorm,
                                                     const int* __restrict__ ambig_cnt,
                                                     const int* __restrict__ ambig,
                                                     float* __restrict__ out_idx_f,
                                                     float* __restrict__ counts8,
                                                     float* __restrict__ loss_ws) {
    int lane = threadIdx.x & 63;
    int wave = (blockIdx.x * 256 + threadIdx.x) >> 6;
    int nw = gridDim.x * 4;
    int cnt = *ambig_cnt;
    for (int a = 2 * wave; a < cnt; a += 2 * nw) {
        int row0 = ambig[a];
        bool two = (a + 1) < cnt;
        int row1 = two ? ambig[a + 1] : row0;
        const float4* zp0 = (const float4*)(z + (size_t)row0 * DIM);
        const float4* zp1 = (const float4*)(z + (size_t)row1 * DIM);
        float4 zr0[16], zr1[16];
        float zn0 = 0.f, zn1 = 0.f;
#pragma unroll
        for (int i = 0; i < 16; ++i) {
            float4 u = zp0[i], v = zp1[i];
            zr0[i] = u; zr1[i] = v;
            zn0 += u.x * u.x + u.y * u.y + u.z * u.z + u.w * u.w;
            zn1 += v.x * v.x + v.y * v.y + v.z * v.z + v.w * v.w;
        }
        float best0 = INFINITY, best1 = INFINITY;
        int bi0 = 0, bi1 = 0;
        for (int j = 0; j < 16; ++j) {
            int code = j * 64 + lane;
            const float4* ep = (const float4*)(E + (size_t)code * DIM);
            float a0 = 0.f, a1 = 0.f, a2 = 0.f, a3 = 0.f;
            float c0 = 0.f, c1 = 0.f, c2 = 0.f, c3 = 0.f;
#pragma unroll
            for (int i = 0; i < 16; ++i) {
                float4 ev = ep[i];
                a0 += zr0[i].x * ev.x; a1 += zr0[i].y * ev.y;
                a2 += zr0[i].z * ev.z; a3 += zr0[i].w * ev.w;
                c0 += zr1[i].x * ev.x; c1 += zr1[i].y * ev.y;
                c2 += zr1[i].z * ev.z; c3 += zr1[i].w * ev.w;
            }
            float en = enorm[code];
            float s0 = en - 2.f * ((a0 + a1) + (a2 + a3));
            float s1 = en - 2.f * ((c0 + c1) + (c2 + c3));
            if (s0 < best0) { best0 = s0; bi0 = code; }
            if (s1 < best1) { best1 = s1; bi1 = code; }
        }
#pragma unroll
        for (int off = 1; off < 64; off <<= 1) {
            float ob = __shfl_xor(best0, off);
            int oi = __shfl_xor(bi0, off);
            if (ob < best0 || (ob == best0 && oi < bi0)) { best0 = ob; bi0 = oi; }
            float ob1 = __shfl_xor(best1, off);
            int oi1 = __shfl_xor(bi1, off);
            if (ob1 < best1 || (ob1 == best1 && oi1 < bi1)) { best1 = ob1; bi1 = oi1; }
        }
        if (lane == 0) {
            out_idx_f[row0] = (float)bi0;
            atomicAdd(&counts8[(((unsigned)row0 >> 8) & 7) * K_CODES + bi0], 1.0f);
            float ladd = zn0 + best0;
            if (two) {
                out_idx_f[row1] = (float)bi1;
                atomicAdd(&counts8[(((unsigned)row1 >> 8) & 7) * K_CODES + bi1], 1.0f);
                ladd += zn1 + best1;
            }
            atomicAdd(loss_ws, ladd);
        }
    }
}

// counts8 -> ncs, n, cs, sharded cursors. Shfl-scan, 2 barriers. (R4 verbatim.)
__global__ __launch_bounds__(1024) void scan_kernel(const float* __restrict__ cluster_size,
                                                    const float* __restrict__ counts8,
                                                    float* __restrict__ ncs_out,
                                                    float* __restrict__ cs_ws,
                                                    int* __restrict__ cursor8) {
    int k = threadIdx.x;
    int lane = k & 63, wv = k >> 6;
    float c8[8];
    float cnt = 0.f;
#pragma unroll
    for (int s = 0; s < 8; ++s) { c8[s] = counts8[s * K_CODES + k]; cnt += c8[s]; }
    float ncs = cluster_size[k] * DECAYF + OMDF * cnt;
    ncs_out[k] = ncs;

    int v = (int)cnt;
    int vs = v;
#pragma unroll
    for (int off = 1; off < 64; off <<= 1) {
        int o = __shfl_up(vs, off, 64);
        if (lane >= off) vs += o;
    }
    float fs = ncs;
#pragma unroll
    for (int off = 1; off < 64; off <<= 1) fs += __shfl_xor(fs, off);

    __shared__ int wtot[16];
    __shared__ float ftot[16];
    __shared__ float nsh;
    if (lane == 63) wtot[wv] = vs;
    if (lane == 0) ftot[wv] = fs;
    __syncthreads();
    if (k == 0) {
        int run = 0; float fn = 0.f;
#pragma unroll
        for (int i = 0; i < 16; ++i) {
            int t = wtot[i]; wtot[i] = run; run += t;
            fn += ftot[i];
        }
        nsh = fn;
    }
    __syncthreads();
    float n = nsh;
    cs_ws[k] = (ncs + EPSF) / (n + (float)K_CODES * EPSF) * n;

    int excl = vs - v + wtot[wv];
    int run = excl;
#pragma unroll
    for (int s = 0; s < 8; ++s) { cursor8[s * K_CODES + k] = run; run += (int)c8[s]; }
}

// Fused scatter + z_q gather-write. (R4 verbatim.)
__global__ __launch_bounds__(256) void scatter_zq_kernel(const float* __restrict__ E,
                                                         const float* __restrict__ idx_f,
                                                         int* __restrict__ cursor8,
                                                         int* __restrict__ order,
                                                         float* __restrict__ zq) {
    __shared__ int s_k[256];
    int tid = threadIdx.x;
    int rbase = blockIdx.x * 256;
    int row = rbase + tid;
    int k = (int)idx_f[row];
    s_k[tid] = k;
    int shard = ((unsigned)row >> 8) & 7;
    int p = atomicAdd(&cursor8[shard * K_CODES + k], 1);
    order[p] = (k << 17) | row;
    __syncthreads();
    size_t ebase = (size_t)rbase * DIM;
#pragma unroll 4
    for (int it = 0; it < 64; ++it) {
        int le = it * 256 + tid;
        int rl = le >> 6, d = le & 63;
        zq[ebase + le] = E[(size_t)s_k[rl] * DIM + d];
    }
}

// Work-partitioned segment sum over the sorted order array. (R4 verbatim.)
__global__ __launch_bounds__(256) void segsum_kernel(const float* __restrict__ z,
                                                     const int* __restrict__ order,
                                                     float* __restrict__ embsum) {
    int lane = threadIdx.x & 63;
    int w = threadIdx.x >> 6;
    int wave = blockIdx.x * 4 + w;
    int base = wave * 64;

    int my = order[base + lane];

    int cur = __shfl(my, 0, 64) >> 17;
    float sum = 0.f;
#pragma unroll 8
    for (int i = 0; i < 64; ++i) {
        int p = __shfl(my, i, 64);
        int row = p & 0x1FFFF;
        int code = p >> 17;
        float v = z[(size_t)row * DIM + lane];
        if (code != cur) {
            atomicAdd(&embsum[(size_t)cur * DIM + lane], sum);
            sum = 0.f;
            cur = code;
        }
        sum += v;
    }
    atomicAdd(&embsum[(size_t)cur * DIM + lane], sum);
}

// EMA epilogue over [K, D] + loss finalize. (R4 verbatim.)
__global__ __launch_bounds__(256) void ema2_kernel(const float* __restrict__ ema,
                                                   const float* __restrict__ embsum,
                                                   const float* __restrict__ cs_ws,
                                                   const float* __restrict__ loss_ws,
                                                   float* __restrict__ newema_out,
                                                   float* __restrict__ newemb_out,
                                                   float* __restrict__ loss_out) {
    int i = blockIdx.x * 256 + threadIdx.x;
    float nes = ema[i] * DECAYF + OMDF * embsum[i];
    newema_out[i] = nes;
    newemb_out[i] = nes / cs_ws[i >> 6];
    if (i == 0)
        loss_out[0] = loss_ws[0] * (1.0f / ((float)N_PTS * (float)DIM));
}

extern "C" void kernel_launch(void* const* d_in, const int* in_sizes, int n_in,
                              void* d_out, int out_size, void* d_ws, size_t ws_size,
                              hipStream_t stream) {
    const float* z            = (const float*)d_in[0];
    const float* E            = (const float*)d_in[1];
    const float* cluster_size = (const float*)d_in[2];
    const float* ema          = (const float*)d_in[3];
    float* out = (float*)d_out;
    float* ws  = (float*)d_ws;

    econv_kernel<<<K_CODES / 64, 256, 0, stream>>>(E, ws);

    argmin_mfma<<<N_PTS / 128, 256, 0, stream>>>(z, (const short*)(ws + WS_E2S),
                                                 out + OUT_IDX,
                                                 ws + WS_C8,
                                                 (int*)(ws + WS_ACNT),
                                                 (int*)(ws + WS_AMBIG),
                                                 ws + WS_LOSS);

    rescue_kernel<<<512, 256, 0, stream>>>(z, E, ws + WS_ENORM,
                                           (const int*)(ws + WS_ACNT),
                                           (const int*)(ws + WS_AMBIG),
                                           out + OUT_IDX,
                                           ws + WS_C8,
                                           ws + WS_LOSS);

    scan_kernel<<<1, 1024, 0, stream>>>(cluster_size, ws + WS_C8,
                                        out + OUT_NEWCS, ws + WS_CS,
                                        (int*)(ws + WS_CUR8));

    scatter_zq_kernel<<<N_PTS / 256, 256, 0, stream>>>(E, out + OUT_IDX,
                                                       (int*)(ws + WS_CUR8),
                                                       (int*)(ws + WS_ORDER),
                                                       out + OUT_ZQ);

    segsum_kernel<<<N_PTS / 256, 256, 0, stream>>>(z,
                                                   (const int*)(ws + WS_ORDER),
                                                   ws + WS_EMBSUM);

    ema2_kernel<<<K_CODES * DIM / 256, 256, 0, stream>>>(ema, ws + WS_EMBSUM,
                                                         ws + WS_CS,
                                                         ws + WS_LOSS,
                                                         out + OUT_NEWEMA,
                                                         out + OUT_NEWEMB,
                                                         out + OUT_LOSS);
}